// Round 15
// baseline (215.272 us; speedup 1.0000x reference)
//
#include <hip/hip_runtime.h>

#define N_FUNC 200000
#define N_API  50000
#define H      64
#define NLAYERS 2
#define NBF 3125   // proj grid: N_FUNC/64
#define NBA 782    // proj grid: ceil(N_API/64)
#define NBF2 1563  // layer grid: ceil(N_FUNC/128)
#define NBA2 391   // layer grid: ceil(N_API/128)
#define PREPB 416  // ceil(106496/256) packed-weight prep blocks
#define NSHADOW 64
#define NBK   391  // buckets per relation
#define BCAP  4096
#define EPB   4096
#define WLOG_F 9
#define WLOG_A 7
#define HCAP  96   // staged edge rows per half-buffer (12KB each)

typedef unsigned short u16;
typedef unsigned int u32;
typedef __bf16 bf16x8 __attribute__((ext_vector_type(8)));
typedef float f32x4 __attribute__((ext_vector_type(4)));
typedef unsigned short u16x8 __attribute__((ext_vector_type(8)));

__device__ __forceinline__ void add4(float4& a, float4 v) {
    a.x += v.x; a.y += v.y; a.z += v.z; a.w += v.w;
}
__device__ __forceinline__ void scl4(float4& a, float s) {
    a.x *= s; a.y *= s; a.z *= s; a.w *= s;
}
__device__ __forceinline__ float bf2f(u16 u) {
    return __uint_as_float(((unsigned int)u) << 16);
}
__device__ __forceinline__ u16 f2bf(float f) {   // RNE
    unsigned int x = __float_as_uint(f);
    return (u16)((x + 0x7FFFu + ((x >> 16) & 1u)) >> 16);
}
__device__ __forceinline__ ushort4 f2b4(float4 o) {
    ushort4 r; r.x = f2bf(o.x); r.y = f2bf(o.y); r.z = f2bf(o.z); r.w = f2bf(o.w);
    return r;
}
__device__ __forceinline__ void addb(float4& a, ushort4 v) {
    a.x += bf2f(v.x); a.y += bf2f(v.y); a.z += bf2f(v.z); a.w += bf2f(v.w);
}

// ==== K1: packed hi/lo bf16 weight prep + binA bucket-scatter (unchanged r14) ====
__global__ __launch_bounds__(256, 6) void prep_and_binA(
        const float* __restrict__ w_in_func, const float* __restrict__ w_in_api,
        const float* __restrict__ Wl_calls, const float* __restrict__ Wr_calls,
        const float* __restrict__ Wl_uses,  const float* __restrict__ Wr_uses,
        const float* __restrict__ Wl_usedby,const float* __restrict__ Wr_usedby,
        u16* __restrict__ wpk,
        const int* __restrict__ sC, const int* __restrict__ dC,
        const int* __restrict__ sU, const int* __restrict__ dU,
        const int* __restrict__ sA, const int* __restrict__ dA,
        int* __restrict__ bktC, int* __restrict__ bktU, int* __restrict__ bktA,
        int* __restrict__ beC, int* __restrict__ beU, int* __restrict__ beA,
        int E, int nbPerRel)
{
    __shared__ int staged[EPB];
    __shared__ int hist[NBK + 1];
    __shared__ int lcnt[NBK];
    __shared__ int gbase[NBK];
    __shared__ int stemp[256];
    const int b = blockIdx.x, t = threadIdx.x;
    if (b < PREPB) {
        int idx = b * 256 + t;
        if (idx < 106496) {
            int half, w, K;
            const float* A; const float* B = nullptr;
            if (idx < 16384) {
                half = idx >> 13; w = idx & 8191; K = 128; A = w_in_func;
            } else if (idx < 24576) {
                int r = idx - 16384;
                half = r >> 12; w = r & 4095; K = 64; A = w_in_api;
            } else {
                int r = idx - 24576;
                int m = r >> 13;
                half = (r >> 12) & 1; w = r & 4095; K = 64;
                int l = m / 5, which = m - 5 * l;
                if (which == 0)      { A = Wr_calls  + l * 4096; B = Wr_usedby + l * 4096; }
                else if (which == 1)   A = Wl_calls  + l * 4096;
                else if (which == 2)   A = Wl_usedby + l * 4096;
                else if (which == 3)   A = Wl_uses   + l * 4096;
                else                   A = Wr_uses   + l * 4096;
            }
            int kt = w >> 11;
            int nt = (w >> 9) & 3;
            int lane = (w >> 3) & 63;
            int i = w & 7;
            int k = kt * 32 + (lane >> 4) * 8 + i;
            int n = nt * 16 + (lane & 15);
            float v = A[n * K + k];
            if (B) v += B[n * K + k];
            u16 hi = f2bf(v);
            wpk[idx] = half ? f2bf(v - bf2f(hi)) : hi;
        }
        return;
    }
    int bb = b - PREPB;
    int rel = bb / nbPerRel, lb = bb - rel * nbPerRel;
    const int* srcA; const int* dstA; int* bcnt; int* be; int wlog;
    if (rel == 0)      { srcA = sC; dstA = dC; bcnt = bktC; be = beC; wlog = WLOG_F; }
    else if (rel == 1) { srcA = sU; dstA = dU; bcnt = bktU; be = beU; wlog = WLOG_F; }
    else               { srcA = sA; dstA = dA; bcnt = bktA; be = beA; wlog = WLOG_A; }
    const int mask = (1 << wlog) - 1;
    const int e0 = lb * EPB;
    const int cnt = min(EPB, E - e0);
    for (int i = t; i < NBK; i += 256) { hist[i] = 0; lcnt[i] = 0; }
    __syncthreads();
    for (int i = t; i < cnt; i += 256)
        atomicAdd(&hist[dstA[e0 + i] >> wlog], 1);
    __syncthreads();
    int v0 = (2 * t < NBK) ? hist[2 * t] : 0;
    int v1 = (2 * t + 1 < NBK) ? hist[2 * t + 1] : 0;
    __syncthreads();
    stemp[t] = v0 + v1; __syncthreads();
    for (int s = 1; s < 256; s <<= 1) {
        int x = (t >= s) ? stemp[t - s] : 0;
        __syncthreads(); stemp[t] += x; __syncthreads();
    }
    int base = (t > 0) ? stemp[t - 1] : 0;
    if (2 * t < NBK)     hist[2 * t] = base;
    if (2 * t + 1 < NBK) hist[2 * t + 1] = base + v0;
    if (t == 255) hist[NBK] = stemp[255];
    __syncthreads();
    for (int i = t; i < cnt; i += 256) {
        int d = dstA[e0 + i], s = srcA[e0 + i];
        int bin = d >> wlog;
        int loc = atomicAdd(&lcnt[bin], 1);
        staged[hist[bin] + loc] = (s << wlog) | (d & mask);
    }
    __syncthreads();
    for (int i = t; i < NBK; i += 256) {
        int c = hist[i + 1] - hist[i];
        gbase[i] = (c > 0) ? atomicAdd(&bcnt[i], c) : 0;
    }
    __syncthreads();
    int wv = t >> 6, ln = t & 63;
    for (int bin = wv; bin < NBK; bin += 4) {
        int l0 = hist[bin], c = hist[bin + 1] - l0;
        int gb = gbase[bin];
        for (int k = ln; k < c; k += 64)
            if (gb + k < BCAP)
                be[(size_t)bin * BCAP + gb + k] = staged[l0 + k];
    }
}

// ==== K2: exclusive scan of 3x391 bucket counts ====
__global__ __launch_bounds__(256) void scan_buckets(
        const int* __restrict__ bktC, const int* __restrict__ bktU, const int* __restrict__ bktA,
        int* __restrict__ bbC, int* __restrict__ bbU, int* __restrict__ bbA)
{
    __shared__ int st[256];
    int t = threadIdx.x;
    for (int r = 0; r < 3; ++r) {
        const int* c = (r == 0) ? bktC : (r == 1) ? bktU : bktA;
        int* B = (r == 0) ? bbC : (r == 1) ? bbU : bbA;
        int v0 = (2 * t < NBK) ? min(c[2 * t], BCAP) : 0;
        int v1 = (2 * t + 1 < NBK) ? min(c[2 * t + 1], BCAP) : 0;
        st[t] = v0 + v1; __syncthreads();
        for (int s = 1; s < 256; s <<= 1) {
            int x = (t >= s) ? st[t - s] : 0;
            __syncthreads(); st[t] += x; __syncthreads();
        }
        int base = (t > 0) ? st[t - 1] : 0;
        if (2 * t < NBK)     B[2 * t] = base;
        if (2 * t + 1 < NBK) B[2 * t + 1] = base + v0;
        __syncthreads();
    }
}

// ---- MFMA proj (unchanged r14) ----
template<int K>
__device__ __forceinline__ void proj_mfma(const float* __restrict__ x,
        const u16* __restrict__ wpk, const float* __restrict__ bias,
        u16* __restrict__ hout, int i0, int nN, u16* Xb)
{
    const int t = threadIdx.x;
    const int wv = t >> 6, lane = t & 63;
    const int row = 16 * wv + (lane & 15);
    const int node = i0 + row;
    constexpr int halfOff = K * 64;
    f32x4 acc[4];
    #pragma unroll
    for (int j = 0; j < 4; ++j) acc[j] = (f32x4){0.f, 0.f, 0.f, 0.f};
    #pragma unroll
    for (int kt = 0; kt < K / 32; ++kt) {
        float v[8];
        if (node < nN) {
            const float* xp = x + (size_t)node * K + kt * 32 + (lane >> 4) * 8;
            #pragma unroll
            for (int i = 0; i < 8; ++i) v[i] = xp[i];
        } else {
            #pragma unroll
            for (int i = 0; i < 8; ++i) v[i] = 0.f;
        }
        u16x8 hh, ll;
        #pragma unroll
        for (int i = 0; i < 8; ++i) {
            u16 h = f2bf(v[i]);
            hh[i] = h;
            ll[i] = f2bf(v[i] - bf2f(h));
        }
        bf16x8 ah = __builtin_bit_cast(bf16x8, hh);
        bf16x8 al = __builtin_bit_cast(bf16x8, ll);
        #pragma unroll
        for (int nt = 0; nt < 4; ++nt) {
            bf16x8 bh = *reinterpret_cast<const bf16x8*>(wpk + (((kt * 4 + nt) * 64 + lane) << 3));
            bf16x8 bl = *reinterpret_cast<const bf16x8*>(wpk + halfOff + (((kt * 4 + nt) * 64 + lane) << 3));
            acc[nt] = __builtin_amdgcn_mfma_f32_16x16x32_bf16(ah, bh, acc[nt], 0, 0, 0);
            acc[nt] = __builtin_amdgcn_mfma_f32_16x16x32_bf16(al, bh, acc[nt], 0, 0, 0);
            acc[nt] = __builtin_amdgcn_mfma_f32_16x16x32_bf16(ah, bl, acc[nt], 0, 0, 0);
        }
    }
    #pragma unroll
    for (int nt = 0; nt < 4; ++nt) {
        int col = nt * 16 + (lane & 15);
        float bvv = bias[col];
        #pragma unroll
        for (int rg = 0; rg < 4; ++rg) {
            int r = 16 * wv + (lane >> 4) * 4 + rg;
            Xb[r * 64 + col] = f2bf(fmaxf(acc[nt][rg] + bvv, 0.f));
        }
    }
    __syncthreads();
    const int og = t & 15, ng = t >> 4;
    #pragma unroll
    for (int j = 0; j < 4; ++j) {
        int node2 = i0 + ng * 4 + j;
        if (node2 < nN) {
            ushort4 v = *reinterpret_cast<const ushort4*>(Xb + (ng * 4 + j) * 64 + og * 4);
            *reinterpret_cast<ushort4*>(hout + (size_t)node2 * H + og * 4) = v;
        }
    }
}

// ==== K3: binB (per-bucket local CSR) + both projections (unchanged r14) ====
__global__ __launch_bounds__(256, 6) void binB_and_proj(
        const int* __restrict__ beC, const int* __restrict__ beU, const int* __restrict__ beA,
        const int* __restrict__ bktC, const int* __restrict__ bktU, const int* __restrict__ bktA,
        const int* __restrict__ bbC, const int* __restrict__ bbU, const int* __restrict__ bbA,
        int* __restrict__ rpC, int* __restrict__ rpU, int* __restrict__ rpA,
        int* __restrict__ colC, int* __restrict__ colU, int* __restrict__ colA,
        const float* __restrict__ xf, const u16* __restrict__ wpkf,
        const float* __restrict__ bf, u16* __restrict__ hf,
        const float* __restrict__ xa, const u16* __restrict__ wpka,
        const float* __restrict__ ba_, u16* __restrict__ ha)
{
    __shared__ __align__(16) int shraw[BCAP + 513 + 512];
    const int b = blockIdx.x, t = threadIdx.x;
    if (b < 3 * NBK) {
        int rel = b / NBK, bkt = b - rel * NBK;
        const int* be; const int* bc; const int* bbs; int* rp; int* col; int wlog, n;
        if (rel == 0)      { be = beC; bc = bktC; bbs = bbC; rp = rpC; col = colC; wlog = WLOG_F; n = N_FUNC; }
        else if (rel == 1) { be = beU; bc = bktU; bbs = bbU; rp = rpU; col = colU; wlog = WLOG_F; n = N_FUNC; }
        else               { be = beA; bc = bktA; bbs = bbA; rp = rpA; col = colA; wlog = WLOG_A; n = N_API; }
        const int width = 1 << wlog, mask = width - 1;
        const int nodeBase = bkt << wlog;
        const int nN = min(width, n - nodeBase);
        const int cnt = min(bc[bkt], BCAP);
        const int gb = bbs[bkt];
        int* colS = shraw;
        int* lrp  = shraw + BCAP;
        int* nxL  = shraw + BCAP + 513;
        for (int i = t; i <= 512; i += 256) { lrp[i] = 0; if (i < 512) nxL[i] = 0; }
        __syncthreads();
        const int* bePtr = be + (size_t)bkt * BCAP;
        for (int i = t; i < cnt; i += 256)
            atomicAdd(&lrp[bePtr[i] & mask], 1);
        __syncthreads();
        int v0 = lrp[2 * t], v1 = lrp[2 * t + 1];
        __syncthreads();
        int* st = colS;
        st[t] = v0 + v1; __syncthreads();
        for (int s = 1; s < 256; s <<= 1) {
            int x = (t >= s) ? st[t - s] : 0;
            __syncthreads(); st[t] += x; __syncthreads();
        }
        int base0 = (t > 0) ? st[t - 1] : 0;
        lrp[2 * t] = base0; lrp[2 * t + 1] = base0 + v0;
        if (t == 255) lrp[512] = st[255];
        __syncthreads();
        for (int i = t; i < nN; i += 256) rp[nodeBase + i] = gb + lrp[i];
        if (nodeBase + nN == n && t == 0) rp[n] = gb + lrp[nN];
        __syncthreads();
        for (int i = t; i < cnt; i += 256) {
            int en = bePtr[i]; int dl = en & mask;
            int pos = lrp[dl] + atomicAdd(&nxL[dl], 1);
            colS[pos] = en >> wlog;
        }
        __syncthreads();
        for (int i = t; i < cnt; i += 256) col[gb + i] = colS[i];
    } else {
        int b2 = b - 3 * NBK;
        u16* Xb = reinterpret_cast<u16*>(shraw);
        if (b2 < NBF) proj_mfma<128>(xf, wpkf, bf, hf, b2 * 64, N_FUNC, Xb);
        else          proj_mfma<64>(xa, wpka, ba_, ha, (b2 - NBF) * 64, N_API, Xb);
    }
}

// ---- async DMA: stage rows [c0,c1) of src via col into a stage half ----
__device__ __forceinline__ void issue_rows(const u16* __restrict__ src_h,
        const int* __restrict__ col, int c0, int c1, u16* half_base, int t)
{
    const int w = t >> 6, lane = t & 63;
    const int cnt = c1 - c0;
    for (int le0 = w * 8; le0 < cnt; le0 += 32) {
        int ge = c0 + min(le0 + (lane >> 3), cnt - 1);
        int srow = col[ge];
        const u16* gp = src_h + (size_t)srow * H + (lane & 7) * 8;
        __builtin_amdgcn_global_load_lds(
            (const __attribute__((address_space(1))) u32*)gp,
            (__attribute__((address_space(3))) u32*)(half_base + le0 * 64),
            16, 0, 0);
    }
}

__device__ __forceinline__ void consume_rows8(const u16* half_base, const int s8[8],
        const int e8[8], int c0, int c1, int L, float4 acc[8])
{
    #pragma unroll
    for (int p = 0; p < 8; ++p) {
        int jlo = max(s8[p], c0), jhi = min(e8[p], c1);
        for (int j = jlo; j < jhi; ++j) {
            ushort4 v = *reinterpret_cast<const ushort4*>(half_base + (size_t)(j - c0) * 64 + L * 4);
            addb(acc[p], v);
        }
    }
}

// ---- MFMA GEMM over 128x64 swizzled bf16 Xb tile ----
__device__ __forceinline__ void gemm_mfma_X128(const u16* Xb, const u16* __restrict__ wpk,
        int wv, int lane, f32x4 acc[2][4])
{
    #pragma unroll
    for (int h = 0; h < 2; ++h) {
        const int r = 32 * wv + 16 * h + (lane & 15);
        #pragma unroll
        for (int kt = 0; kt < 2; ++kt) {
            bf16x8 a = *reinterpret_cast<const bf16x8*>(
                Xb + r * 64 + (((kt * 4 + (lane >> 4)) ^ (r & 7)) << 3));
            #pragma unroll
            for (int nt = 0; nt < 4; ++nt) {
                bf16x8 bh = *reinterpret_cast<const bf16x8*>(wpk + ((kt * 256 + nt * 64 + lane) << 3));
                acc[h][nt] = __builtin_amdgcn_mfma_f32_16x16x32_bf16(a, bh, acc[h][nt], 0, 0, 0);
                bf16x8 bl = *reinterpret_cast<const bf16x8*>(wpk + 4096 + ((kt * 256 + nt * 64 + lane) << 3));
                acc[h][nt] = __builtin_amdgcn_mfma_f32_16x16x32_bf16(a, bl, acc[h][nt], 0, 0, 0);
            }
        }
    }
}

// ---- MFMA GEMM, A-frags in registers (own rows, loaded direct from global) ----
__device__ __forceinline__ void gemm_mfma_R128(const bf16x8 ao[2][2], const u16* __restrict__ wpk,
        int lane, f32x4 acc[2][4])
{
    #pragma unroll
    for (int h = 0; h < 2; ++h) {
        #pragma unroll
        for (int kt = 0; kt < 2; ++kt) {
            #pragma unroll
            for (int nt = 0; nt < 4; ++nt) {
                bf16x8 bh = *reinterpret_cast<const bf16x8*>(wpk + ((kt * 256 + nt * 64 + lane) << 3));
                acc[h][nt] = __builtin_amdgcn_mfma_f32_16x16x32_bf16(ao[h][kt], bh, acc[h][nt], 0, 0, 0);
                bf16x8 bl = *reinterpret_cast<const bf16x8*>(wpk + 4096 + ((kt * 256 + nt * 64 + lane) << 3));
                acc[h][nt] = __builtin_amdgcn_mfma_f32_16x16x32_bf16(ao[h][kt], bl, acc[h][nt], 0, 0, 0);
            }
        }
    }
}

__device__ __forceinline__ void store_agg(u16* Xb, int n, int L, float4 a)
{
    *reinterpret_cast<ushort4*>(Xb + n * 64 + (((L >> 1) ^ (n & 7)) << 3) + ((L & 1) << 2)) = f2b4(a);
}

// ---- fused layer: 128-node tiles, A/B pipelined DMA gather, MFMA GEMMs ----
__global__ __launch_bounds__(256, 4) void layer_both(
        const u16* __restrict__ hf_old, const u16* __restrict__ ha_old,
        u16* __restrict__ hf_new, u16* __restrict__ ha_new,
        const int* __restrict__ rpC, const int* __restrict__ colC,
        const int* __restrict__ rpU, const int* __restrict__ colU,
        const int* __restrict__ rpA, const int* __restrict__ colA,
        const u16* __restrict__ pk_r, const u16* __restrict__ pk_lc,
        const u16* __restrict__ pk_lu,
        const u16* __restrict__ pk_ruse, const u16* __restrict__ pk_luse,
        const float* __restrict__ bias_c, const float* __restrict__ bias_u,
        const float* __restrict__ bias_a,
        float* __restrict__ psh)
{
    __shared__ __align__(16) u16 Xb[128 * 64];          // 16 KB bf16 tile
    __shared__ __align__(16) u16 stage[2 * HCAP * 64];  // 2 x 12 KB halves
    const int b = blockIdx.x;
    const int t = threadIdx.x;
    const int L = t & 15, g = t >> 4;
    const int wv = t >> 6, lane = t & 63;
    const float4 z4 = make_float4(0.f, 0.f, 0.f, 0.f);

    f32x4 acc[2][4];
    #pragma unroll
    for (int h = 0; h < 2; ++h)
        #pragma unroll
        for (int j = 0; j < 4; ++j) acc[h][j] = (f32x4){0.f, 0.f, 0.f, 0.f};

    int buf = 0;
    if (b < NBF2) {
        const int i0 = b * 128;
        // ---- P1: calls gather (A/B pipelined) ----
        {
            int s1[8], e1[8]; float4 a1[8];
            #pragma unroll
            for (int p = 0; p < 8; ++p) {
                int node = i0 + p * 16 + g;
                s1[p] = rpC[node]; e1[p] = rpC[node + 1];
                a1[p] = z4;
            }
            const int be0 = rpC[i0], be1 = rpC[i0 + 128];
            int c0 = be0, c1 = min(c0 + HCAP, be1);
            if (c0 < be1) issue_rows(hf_old, colC, c0, c1, stage, t);
            while (c0 < be1) {
                __syncthreads();
                int n0 = c1, n1 = min(n0 + HCAP, be1);
                if (n0 < be1) issue_rows(hf_old, colC, n0, n1, stage + (buf ^ 1) * (HCAP * 64), t);
                consume_rows8(stage + buf * (HCAP * 64), s1, e1, c0, c1, L, a1);
                c0 = n0; c1 = n1; buf ^= 1;
            }
            #pragma unroll
            for (int p = 0; p < 8; ++p) {
                int n = p * 16 + g;
                scl4(a1[p], 1.0f / (float)max(e1[p] - s1[p], 1));
                store_agg(Xb, n, L, a1[p]);
            }
        }
        __syncthreads();   // agg1 visible; all P1 consumes done
        // ---- P2 prefetch chunk0, gemm1 hides flight ----
        int s2[8], e2[8];
        #pragma unroll
        for (int p = 0; p < 8; ++p) {
            int node = i0 + p * 16 + g;
            s2[p] = rpU[node]; e2[p] = rpU[node + 1];
        }
        const int ue0 = rpU[i0], ue1 = rpU[i0 + 128];
        int c0 = ue0, c1 = min(c0 + HCAP, ue1);
        if (c0 < ue1) issue_rows(ha_old, colU, c0, c1, stage + buf * (HCAP * 64), t);
        gemm_mfma_X128(Xb, pk_lc, wv, lane, acc);
        {
            float4 a2[8];
            #pragma unroll
            for (int p = 0; p < 8; ++p) a2[p] = z4;
            while (c0 < ue1) {
                __syncthreads();
                int n0 = c1, n1 = min(n0 + HCAP, ue1);
                if (n0 < ue1) issue_rows(ha_old, colU, n0, n1, stage + (buf ^ 1) * (HCAP * 64), t);
                consume_rows8(stage + buf * (HCAP * 64), s2, e2, c0, c1, L, a2);
                c0 = n0; c1 = n1; buf ^= 1;
            }
            __syncthreads();   // gemm1 + P2 consumes done: Xb free
            #pragma unroll
            for (int p = 0; p < 8; ++p) {
                int n = p * 16 + g;
                scl4(a2[p], 1.0f / (float)max(e2[p] - s2[p], 1));
                store_agg(Xb, n, L, a2[p]);
            }
        }
        __syncthreads();   // agg2 visible
        // ---- own-row A frags direct from global; gemm2 hides latency ----
        bf16x8 ao[2][2];
        #pragma unroll
        for (int h = 0; h < 2; ++h) {
            int r = 32 * wv + 16 * h + (lane & 15);
            #pragma unroll
            for (int kt = 0; kt < 2; ++kt)
                ao[h][kt] = *reinterpret_cast<const bf16x8*>(
                    hf_old + (size_t)(i0 + r) * H + kt * 32 + ((lane >> 4) << 3));
        }
        gemm_mfma_X128(Xb, pk_lu, wv, lane, acc);
        gemm_mfma_R128(ao, pk_r, lane, acc);
        __syncthreads();   // Xb free for C
        #pragma unroll
        for (int nt = 0; nt < 4; ++nt) {
            int col = nt * 16 + (lane & 15);
            float bvv = bias_c[col] + bias_u[col];
            #pragma unroll
            for (int h = 0; h < 2; ++h) {
                #pragma unroll
                for (int rg = 0; rg < 4; ++rg) {
                    int row = 32 * wv + 16 * h + (lane >> 4) * 4 + rg;
                    Xb[row * 64 + col] = f2bf(fmaxf(acc[h][nt][rg] + bvv, 0.f));
                }
            }
        }
        __syncthreads();
        const int og = t & 15, ng = t >> 4;
        float4 s = z4;
        #pragma unroll
        for (int j = 0; j < 8; ++j) {
            int node = i0 + ng * 8 + j;
            ushort4 v = *reinterpret_cast<const ushort4*>(Xb + (ng * 8 + j) * 64 + og * 4);
            *reinterpret_cast<ushort4*>(hf_new + (size_t)node * H + og * 4) = v;
            if (psh) addb(s, v);
        }
        if (psh) {
            __syncthreads();
            float4* X4 = reinterpret_cast<float4*>(Xb);
            X4[ng * 16 + og] = s;
            __syncthreads();
            if (ng == 0) {
                float4 tot = z4;
                #pragma unroll
                for (int q = 0; q < 16; ++q) add4(tot, X4[q * 16 + og]);
                float* dst = psh + (size_t)(b & (NSHADOW - 1)) * 128 + og * 4;
                atomicAdd(dst + 0, tot.x); atomicAdd(dst + 1, tot.y);
                atomicAdd(dst + 2, tot.z); atomicAdd(dst + 3, tot.w);
            }
        }
    } else {
        const int i0 = (b - NBF2) * 128;
        const int nTop = min(i0 + 128, N_API);
        {
            int s1[8], e1[8]; float4 a1[8];
            #pragma unroll
            for (int p = 0; p < 8; ++p) {
                int node = i0 + p * 16 + g;
                if (node < N_API) { s1[p] = rpA[node]; e1[p] = rpA[node + 1]; }
                else { s1[p] = 0; e1[p] = 0; }
                a1[p] = z4;
            }
            const int be0 = rpA[i0], be1 = rpA[nTop];
            int c0 = be0, c1 = min(c0 + HCAP, be1);
            if (c0 < be1) issue_rows(hf_old, colA, c0, c1, stage, t);
            while (c0 < be1) {
                __syncthreads();
                int n0 = c1, n1 = min(n0 + HCAP, be1);
                if (n0 < be1) issue_rows(hf_old, colA, n0, n1, stage + (buf ^ 1) * (HCAP * 64), t);
                consume_rows8(stage + buf * (HCAP * 64), s1, e1, c0, c1, L, a1);
                c0 = n0; c1 = n1; buf ^= 1;
            }
            #pragma unroll
            for (int p = 0; p < 8; ++p) {
                int n = p * 16 + g;
                scl4(a1[p], 1.0f / (float)max(e1[p] - s1[p], 1));
                store_agg(Xb, n, L, a1[p]);
            }
        }
        __syncthreads();
        // own-row frags; gemm1 hides
        bf16x8 ao[2][2];
        #pragma unroll
        for (int h = 0; h < 2; ++h) {
            int r = 32 * wv + 16 * h + (lane & 15);
            #pragma unroll
            for (int kt = 0; kt < 2; ++kt) {
                if (i0 + r < N_API) {
                    ao[h][kt] = *reinterpret_cast<const bf16x8*>(
                        ha_old + (size_t)(i0 + r) * H + kt * 32 + ((lane >> 4) << 3));
                } else {
                    u16x8 zz = (u16x8){0,0,0,0,0,0,0,0};
                    ao[h][kt] = __builtin_bit_cast(bf16x8, zz);
                }
            }
        }
        gemm_mfma_X128(Xb, pk_luse, wv, lane, acc);
        gemm_mfma_R128(ao, pk_ruse, lane, acc);
        __syncthreads();
        #pragma unroll
        for (int nt = 0; nt < 4; ++nt) {
            int col = nt * 16 + (lane & 15);
            float bvv = bias_a[col];
            #pragma unroll
            for (int h = 0; h < 2; ++h) {
                #pragma unroll
                for (int rg = 0; rg < 4; ++rg) {
                    int row = 32 * wv + 16 * h + (lane >> 4) * 4 + rg;
                    Xb[row * 64 + col] = f2bf(fmaxf(acc[h][nt][rg] + bvv, 0.f));
                }
            }
        }
        __syncthreads();
        const int og = t & 15, ng = t >> 4;
        float4 s = z4;
        #pragma unroll
        for (int j = 0; j < 8; ++j) {
            int node = i0 + ng * 8 + j;
            if (node < N_API) {
                ushort4 v = *reinterpret_cast<const ushort4*>(Xb + (ng * 8 + j) * 64 + og * 4);
                *reinterpret_cast<ushort4*>(ha_new + (size_t)node * H + og * 4) = v;
                if (psh) addb(s, v);
            }
        }
        if (psh) {
            __syncthreads();
            float4* X4 = reinterpret_cast<float4*>(Xb);
            X4[ng * 16 + og] = s;
            __syncthreads();
            if (ng == 0) {
                float4 tot = z4;
                #pragma unroll
                for (int q = 0; q < 16; ++q) add4(tot, X4[q * 16 + og]);
                float* dst = psh + (size_t)(b & (NSHADOW - 1)) * 128 + 64 + og * 4;
                atomicAdd(dst + 0, tot.x); atomicAdd(dst + 1, tot.y);
                atomicAdd(dst + 2, tot.z); atomicAdd(dst + 3, tot.w);
            }
        }
    }
}

__global__ __launch_bounds__(128) void classifier_kernel(const float* __restrict__ shadows,
        const float* __restrict__ Wc1, const float* __restrict__ bc1,
        const float* __restrict__ Wc2, const float* __restrict__ bc2,
        float* __restrict__ out)
{
    __shared__ float ps[128];
    __shared__ float z1[64];
    int t = threadIdx.x;
    float s = 0.f;
    for (int q = 0; q < NSHADOW; ++q) s += shadows[q * 128 + t];
    ps[t] = s * (t < 64 ? (1.0f / N_FUNC) : (1.0f / N_API));
    __syncthreads();
    if (t < 64) {
        float a = bc1[t];
        for (int k = 0; k < 128; ++k) a = fmaf(ps[k], Wc1[t * 128 + k], a);
        z1[t] = fmaxf(a, 0.f);
    }
    __syncthreads();
    if (t < 2) {
        float a = bc2[t];
        for (int j = 0; j < 64; ++j) a = fmaf(z1[j], Wc2[t * 64 + j], a);
        out[t] = a;
    }
}

extern "C" void kernel_launch(void* const* d_in, const int* in_sizes, int n_in,
                              void* d_out, int out_size, void* d_ws, size_t ws_size,
                              hipStream_t stream)
{
    const float* x_func    = (const float*)d_in[0];
    const float* x_api     = (const float*)d_in[1];
    const float* w_in_func = (const float*)d_in[2];
    const float* b_in_func = (const float*)d_in[3];
    const float* w_in_api  = (const float*)d_in[4];
    const float* b_in_api  = (const float*)d_in[5];
    const float* Wl_calls  = (const float*)d_in[6];
    const float* bl_calls  = (const float*)d_in[7];
    const float* Wr_calls  = (const float*)d_in[8];
    const float* Wl_uses   = (const float*)d_in[9];
    const float* bl_uses   = (const float*)d_in[10];
    const float* Wr_uses   = (const float*)d_in[11];
    const float* Wl_usedby = (const float*)d_in[12];
    const float* bl_usedby = (const float*)d_in[13];
    const float* Wr_usedby = (const float*)d_in[14];
    const float* Wc1       = (const float*)d_in[15];
    const float* bc1       = (const float*)d_in[16];
    const float* Wc2       = (const float*)d_in[17];
    const float* bc2       = (const float*)d_in[18];
    const int*   ei_calls  = (const int*)d_in[19];
    const int*   ei_uses   = (const int*)d_in[20];
    const int*   ei_usedby = (const int*)d_in[21];
    const int E = in_sizes[19] / 2;

    float* ws = (float*)d_ws;
    size_t off = 0;
    u16* hf0 = (u16*)(ws + off); off += (size_t)N_FUNC * 32;
    u16* hf1 = (u16*)(ws + off); off += (size_t)N_FUNC * 32;
    u16* ha0 = (u16*)(ws + off); off += (size_t)N_API * 32;
    u16* ha1 = (u16*)(ws + off); off += (size_t)N_API * 32;
    u16* wpk = (u16*)(ws + off); off += 53248;   // 106496 u16 packed weights
    int* bktC = (int*)(ws + off); off += NBK;
    int* bktU = (int*)(ws + off); off += NBK;
    int* bktA = (int*)(ws + off); off += NBK;
    float* shadows = ws + off; off += NSHADOW * 128;
    int* bbC = (int*)(ws + off); off += NBK;
    int* bbU = (int*)(ws + off); off += NBK;
    int* bbA = (int*)(ws + off); off += NBK;
    int* rpC = (int*)(ws + off); off += N_FUNC + 1;
    int* rpU = (int*)(ws + off); off += N_FUNC + 1;
    int* rpA = (int*)(ws + off); off += N_API + 1;
    int* colC = (int*)(ws + off); off += E;
    int* colU = (int*)(ws + off); off += E;
    int* colA = (int*)(ws + off); off += E;
    int* beC = (int*)(ws + off); off += (size_t)NBK * BCAP;
    int* beU = (int*)(ws + off); off += (size_t)NBK * BCAP;
    int* beA = (int*)(ws + off); off += (size_t)NBK * BCAP;

    const int nbPerRel = (E + EPB - 1) / EPB;

    hipMemsetAsync(bktC, 0, (size_t)(3 * NBK + NSHADOW * 128) * sizeof(float), stream);

    prep_and_binA<<<PREPB + 3 * nbPerRel, 256, 0, stream>>>(
            w_in_func, w_in_api, Wl_calls, Wr_calls, Wl_uses, Wr_uses,
            Wl_usedby, Wr_usedby, wpk,
            ei_calls, ei_calls + E, ei_usedby, ei_usedby + E, ei_uses, ei_uses + E,
            bktC, bktU, bktA, beC, beU, beA, E, nbPerRel);

    scan_buckets<<<1, 256, 0, stream>>>(bktC, bktU, bktA, bbC, bbU, bbA);

    u16* wpkf = wpk;
    u16* wpka = wpk + 16384;
    u16* wpkL = wpk + 24576;
    u16 *pk_r[NLAYERS], *pk_lc[NLAYERS], *pk_lu[NLAYERS], *pk_luse[NLAYERS], *pk_ruse[NLAYERS];
    for (int l = 0; l < NLAYERS; ++l) {
        pk_r[l]    = wpkL + (size_t)(l * 5 + 0) * 8192;
        pk_lc[l]   = wpkL + (size_t)(l * 5 + 1) * 8192;
        pk_lu[l]   = wpkL + (size_t)(l * 5 + 2) * 8192;
        pk_luse[l] = wpkL + (size_t)(l * 5 + 3) * 8192;
        pk_ruse[l] = wpkL + (size_t)(l * 5 + 4) * 8192;
    }

    binB_and_proj<<<3 * NBK + NBF + NBA, 256, 0, stream>>>(
            beC, beU, beA, bktC, bktU, bktA, bbC, bbU, bbA,
            rpC, rpU, rpA, colC, colU, colA,
            x_func, wpkf, b_in_func, hf0,
            x_api, wpka, b_in_api, ha0);

    u16* hf[2] = { hf0, hf1 };
    u16* ha[2] = { ha0, ha1 };
    for (int l = 0; l < NLAYERS; ++l) {
        int cur = l & 1, nxt = cur ^ 1;
        layer_both<<<NBF2 + NBA2, 256, 0, stream>>>(
                hf[cur], ha[cur], hf[nxt], ha[nxt],
                rpC, colC, rpU, colU, rpA, colA,
                pk_r[l], pk_lc[l], pk_lu[l], pk_ruse[l], pk_luse[l],
                bl_calls + l * 64, bl_usedby + l * 64, bl_uses + l * 64,
                (l == NLAYERS - 1) ? shadows : nullptr);
    }

    classifier_kernel<<<1, 128, 0, stream>>>(shadows, Wc1, bc1, Wc2, bc2, (float*)d_out);
}

// Round 16
// 205.379 us; speedup vs baseline: 1.0482x; 1.0482x over previous
//
#include <hip/hip_runtime.h>

#define N_FUNC 200000
#define N_API  50000
#define H      64
#define NLAYERS 2
#define NBF 3125   // N_FUNC/64 exact
#define NBA 782    // ceil(N_API/64)
#define PREPB 416  // ceil(106496/256) packed-weight prep blocks
#define NSHADOW 64
#define NBK   391  // buckets per relation
#define BCAP  4096
#define EPB   4096
#define WLOG_F 9
#define WLOG_A 7
#define SCAP  160  // staged edge rows per chunk (20KB; 28KB total LDS -> 5 blocks/CU)

typedef unsigned short u16;
typedef unsigned int u32;
typedef __bf16 bf16x8 __attribute__((ext_vector_type(8)));
typedef float f32x4 __attribute__((ext_vector_type(4)));
typedef unsigned short u16x8 __attribute__((ext_vector_type(8)));

__device__ __forceinline__ void add4(float4& a, float4 v) {
    a.x += v.x; a.y += v.y; a.z += v.z; a.w += v.w;
}
__device__ __forceinline__ void scl4(float4& a, float s) {
    a.x *= s; a.y *= s; a.z *= s; a.w *= s;
}
__device__ __forceinline__ float bf2f(u16 u) {
    return __uint_as_float(((unsigned int)u) << 16);
}
__device__ __forceinline__ u16 f2bf(float f) {   // RNE
    unsigned int x = __float_as_uint(f);
    return (u16)((x + 0x7FFFu + ((x >> 16) & 1u)) >> 16);
}
__device__ __forceinline__ ushort4 f2b4(float4 o) {
    ushort4 r; r.x = f2bf(o.x); r.y = f2bf(o.y); r.z = f2bf(o.z); r.w = f2bf(o.w);
    return r;
}
__device__ __forceinline__ void addb(float4& a, ushort4 v) {
    a.x += bf2f(v.x); a.y += bf2f(v.y); a.z += bf2f(v.z); a.w += bf2f(v.w);
}

// ==== K1: packed hi/lo bf16 weight prep (proj + layers) + binA bucket-scatter ====
__global__ __launch_bounds__(256, 6) void prep_and_binA(
        const float* __restrict__ w_in_func, const float* __restrict__ w_in_api,
        const float* __restrict__ Wl_calls, const float* __restrict__ Wr_calls,
        const float* __restrict__ Wl_uses,  const float* __restrict__ Wr_uses,
        const float* __restrict__ Wl_usedby,const float* __restrict__ Wr_usedby,
        u16* __restrict__ wpk,
        const int* __restrict__ sC, const int* __restrict__ dC,
        const int* __restrict__ sU, const int* __restrict__ dU,
        const int* __restrict__ sA, const int* __restrict__ dA,
        int* __restrict__ bktC, int* __restrict__ bktU, int* __restrict__ bktA,
        int* __restrict__ beC, int* __restrict__ beU, int* __restrict__ beA,
        int E, int nbPerRel)
{
    __shared__ int staged[EPB];
    __shared__ int hist[NBK + 1];
    __shared__ int lcnt[NBK];
    __shared__ int gbase[NBK];
    __shared__ int stemp[256];
    const int b = blockIdx.x, t = threadIdx.x;
    if (b < PREPB) {
        int idx = b * 256 + t;
        if (idx < 106496) {
            int half, w, K;
            const float* A; const float* B = nullptr;
            if (idx < 16384) {
                half = idx >> 13; w = idx & 8191; K = 128; A = w_in_func;
            } else if (idx < 24576) {
                int r = idx - 16384;
                half = r >> 12; w = r & 4095; K = 64; A = w_in_api;
            } else {
                int r = idx - 24576;
                int m = r >> 13;
                half = (r >> 12) & 1; w = r & 4095; K = 64;
                int l = m / 5, which = m - 5 * l;
                if (which == 0)      { A = Wr_calls  + l * 4096; B = Wr_usedby + l * 4096; }
                else if (which == 1)   A = Wl_calls  + l * 4096;
                else if (which == 2)   A = Wl_usedby + l * 4096;
                else if (which == 3)   A = Wl_uses   + l * 4096;
                else                   A = Wr_uses   + l * 4096;
            }
            int kt = w >> 11;
            int nt = (w >> 9) & 3;
            int lane = (w >> 3) & 63;
            int i = w & 7;
            int k = kt * 32 + (lane >> 4) * 8 + i;
            int n = nt * 16 + (lane & 15);
            float v = A[n * K + k];
            if (B) v += B[n * K + k];
            u16 hi = f2bf(v);
            wpk[idx] = half ? f2bf(v - bf2f(hi)) : hi;
        }
        return;
    }
    int bb = b - PREPB;
    int rel = bb / nbPerRel, lb = bb - rel * nbPerRel;
    const int* srcA; const int* dstA; int* bcnt; int* be; int wlog;
    if (rel == 0)      { srcA = sC; dstA = dC; bcnt = bktC; be = beC; wlog = WLOG_F; }
    else if (rel == 1) { srcA = sU; dstA = dU; bcnt = bktU; be = beU; wlog = WLOG_F; }
    else               { srcA = sA; dstA = dA; bcnt = bktA; be = beA; wlog = WLOG_A; }
    const int mask = (1 << wlog) - 1;
    const int e0 = lb * EPB;
    const int cnt = min(EPB, E - e0);
    for (int i = t; i < NBK; i += 256) { hist[i] = 0; lcnt[i] = 0; }
    __syncthreads();
    for (int i = t; i < cnt; i += 256)
        atomicAdd(&hist[dstA[e0 + i] >> wlog], 1);
    __syncthreads();
    int v0 = (2 * t < NBK) ? hist[2 * t] : 0;
    int v1 = (2 * t + 1 < NBK) ? hist[2 * t + 1] : 0;
    __syncthreads();
    stemp[t] = v0 + v1; __syncthreads();
    for (int s = 1; s < 256; s <<= 1) {
        int x = (t >= s) ? stemp[t - s] : 0;
        __syncthreads(); stemp[t] += x; __syncthreads();
    }
    int base = (t > 0) ? stemp[t - 1] : 0;
    if (2 * t < NBK)     hist[2 * t] = base;
    if (2 * t + 1 < NBK) hist[2 * t + 1] = base + v0;
    if (t == 255) hist[NBK] = stemp[255];
    __syncthreads();
    for (int i = t; i < cnt; i += 256) {
        int d = dstA[e0 + i], s = srcA[e0 + i];
        int bin = d >> wlog;
        int loc = atomicAdd(&lcnt[bin], 1);
        staged[hist[bin] + loc] = (s << wlog) | (d & mask);
    }
    __syncthreads();
    for (int i = t; i < NBK; i += 256) {
        int c = hist[i + 1] - hist[i];
        gbase[i] = (c > 0) ? atomicAdd(&bcnt[i], c) : 0;
    }
    __syncthreads();
    int wv = t >> 6, ln = t & 63;
    for (int bin = wv; bin < NBK; bin += 4) {
        int l0 = hist[bin], c = hist[bin + 1] - l0;
        int gb = gbase[bin];
        for (int k = ln; k < c; k += 64)
            if (gb + k < BCAP)
                be[(size_t)bin * BCAP + gb + k] = staged[l0 + k];
    }
}

// ==== K2: exclusive scan of 3x391 bucket counts ====
__global__ __launch_bounds__(256) void scan_buckets(
        const int* __restrict__ bktC, const int* __restrict__ bktU, const int* __restrict__ bktA,
        int* __restrict__ bbC, int* __restrict__ bbU, int* __restrict__ bbA)
{
    __shared__ int st[256];
    int t = threadIdx.x;
    for (int r = 0; r < 3; ++r) {
        const int* c = (r == 0) ? bktC : (r == 1) ? bktU : bktA;
        int* B = (r == 0) ? bbC : (r == 1) ? bbU : bbA;
        int v0 = (2 * t < NBK) ? min(c[2 * t], BCAP) : 0;
        int v1 = (2 * t + 1 < NBK) ? min(c[2 * t + 1], BCAP) : 0;
        st[t] = v0 + v1; __syncthreads();
        for (int s = 1; s < 256; s <<= 1) {
            int x = (t >= s) ? st[t - s] : 0;
            __syncthreads(); st[t] += x; __syncthreads();
        }
        int base = (t > 0) ? st[t - 1] : 0;
        if (2 * t < NBK)     B[2 * t] = base;
        if (2 * t + 1 < NBK) B[2 * t + 1] = base + v0;
        __syncthreads();
    }
}

// ---- MFMA proj: x (fp32, hi/lo split in-register) @ W (packed hi/lo bf16) ----
template<int K>
__device__ __forceinline__ void proj_mfma(const float* __restrict__ x,
        const u16* __restrict__ wpk, const float* __restrict__ bias,
        u16* __restrict__ hout, int i0, int nN, u16* Xb)
{
    const int t = threadIdx.x;
    const int wv = t >> 6, lane = t & 63;
    const int row = 16 * wv + (lane & 15);
    const int node = i0 + row;
    constexpr int halfOff = K * 64;
    f32x4 acc[4];
    #pragma unroll
    for (int j = 0; j < 4; ++j) acc[j] = (f32x4){0.f, 0.f, 0.f, 0.f};
    #pragma unroll
    for (int kt = 0; kt < K / 32; ++kt) {
        float v[8];
        if (node < nN) {
            const float* xp = x + (size_t)node * K + kt * 32 + (lane >> 4) * 8;
            #pragma unroll
            for (int i = 0; i < 8; ++i) v[i] = xp[i];
        } else {
            #pragma unroll
            for (int i = 0; i < 8; ++i) v[i] = 0.f;
        }
        u16x8 hh, ll;
        #pragma unroll
        for (int i = 0; i < 8; ++i) {
            u16 h = f2bf(v[i]);
            hh[i] = h;
            ll[i] = f2bf(v[i] - bf2f(h));
        }
        bf16x8 ah = __builtin_bit_cast(bf16x8, hh);
        bf16x8 al = __builtin_bit_cast(bf16x8, ll);
        #pragma unroll
        for (int nt = 0; nt < 4; ++nt) {
            bf16x8 bh = *reinterpret_cast<const bf16x8*>(wpk + (((kt * 4 + nt) * 64 + lane) << 3));
            bf16x8 bl = *reinterpret_cast<const bf16x8*>(wpk + halfOff + (((kt * 4 + nt) * 64 + lane) << 3));
            acc[nt] = __builtin_amdgcn_mfma_f32_16x16x32_bf16(ah, bh, acc[nt], 0, 0, 0);
            acc[nt] = __builtin_amdgcn_mfma_f32_16x16x32_bf16(al, bh, acc[nt], 0, 0, 0);
            acc[nt] = __builtin_amdgcn_mfma_f32_16x16x32_bf16(ah, bl, acc[nt], 0, 0, 0);
        }
    }
    #pragma unroll
    for (int nt = 0; nt < 4; ++nt) {
        int col = nt * 16 + (lane & 15);
        float bvv = bias[col];
        #pragma unroll
        for (int rg = 0; rg < 4; ++rg) {
            int r = 16 * wv + (lane >> 4) * 4 + rg;
            Xb[r * 64 + col] = f2bf(fmaxf(acc[nt][rg] + bvv, 0.f));
        }
    }
    __syncthreads();
    const int og = t & 15, ng = t >> 4;
    #pragma unroll
    for (int j = 0; j < 4; ++j) {
        int node2 = i0 + ng * 4 + j;
        if (node2 < nN) {
            ushort4 v = *reinterpret_cast<const ushort4*>(Xb + (ng * 4 + j) * 64 + og * 4);
            *reinterpret_cast<ushort4*>(hout + (size_t)node2 * H + og * 4) = v;
        }
    }
}

// ==== K3: binB (per-bucket local CSR) + both projections (MFMA) ====
__global__ __launch_bounds__(256, 6) void binB_and_proj(
        const int* __restrict__ beC, const int* __restrict__ beU, const int* __restrict__ beA,
        const int* __restrict__ bktC, const int* __restrict__ bktU, const int* __restrict__ bktA,
        const int* __restrict__ bbC, const int* __restrict__ bbU, const int* __restrict__ bbA,
        int* __restrict__ rpC, int* __restrict__ rpU, int* __restrict__ rpA,
        int* __restrict__ colC, int* __restrict__ colU, int* __restrict__ colA,
        const float* __restrict__ xf, const u16* __restrict__ wpkf,
        const float* __restrict__ bf, u16* __restrict__ hf,
        const float* __restrict__ xa, const u16* __restrict__ wpka,
        const float* __restrict__ ba_, u16* __restrict__ ha)
{
    __shared__ __align__(16) int shraw[BCAP + 513 + 512];
    const int b = blockIdx.x, t = threadIdx.x;
    if (b < 3 * NBK) {
        int rel = b / NBK, bkt = b - rel * NBK;
        const int* be; const int* bc; const int* bbs; int* rp; int* col; int wlog, n;
        if (rel == 0)      { be = beC; bc = bktC; bbs = bbC; rp = rpC; col = colC; wlog = WLOG_F; n = N_FUNC; }
        else if (rel == 1) { be = beU; bc = bktU; bbs = bbU; rp = rpU; col = colU; wlog = WLOG_F; n = N_FUNC; }
        else               { be = beA; bc = bktA; bbs = bbA; rp = rpA; col = colA; wlog = WLOG_A; n = N_API; }
        const int width = 1 << wlog, mask = width - 1;
        const int nodeBase = bkt << wlog;
        const int nN = min(width, n - nodeBase);
        const int cnt = min(bc[bkt], BCAP);
        const int gb = bbs[bkt];
        int* colS = shraw;
        int* lrp  = shraw + BCAP;
        int* nxL  = shraw + BCAP + 513;
        for (int i = t; i <= 512; i += 256) { lrp[i] = 0; if (i < 512) nxL[i] = 0; }
        __syncthreads();
        const int* bePtr = be + (size_t)bkt * BCAP;
        for (int i = t; i < cnt; i += 256)
            atomicAdd(&lrp[bePtr[i] & mask], 1);
        __syncthreads();
        int v0 = lrp[2 * t], v1 = lrp[2 * t + 1];
        __syncthreads();
        int* st = colS;
        st[t] = v0 + v1; __syncthreads();
        for (int s = 1; s < 256; s <<= 1) {
            int x = (t >= s) ? st[t - s] : 0;
            __syncthreads(); st[t] += x; __syncthreads();
        }
        int base0 = (t > 0) ? st[t - 1] : 0;
        lrp[2 * t] = base0; lrp[2 * t + 1] = base0 + v0;
        if (t == 255) lrp[512] = st[255];
        __syncthreads();
        for (int i = t; i < nN; i += 256) rp[nodeBase + i] = gb + lrp[i];
        if (nodeBase + nN == n && t == 0) rp[n] = gb + lrp[nN];
        __syncthreads();
        for (int i = t; i < cnt; i += 256) {
            int en = bePtr[i]; int dl = en & mask;
            int pos = lrp[dl] + atomicAdd(&nxL[dl], 1);
            colS[pos] = en >> wlog;
        }
        __syncthreads();
        for (int i = t; i < cnt; i += 256) col[gb + i] = colS[i];
    } else {
        int b2 = b - 3 * NBK;
        u16* Xb = reinterpret_cast<u16*>(shraw);
        if (b2 < NBF) proj_mfma<128>(xf, wpkf, bf, hf, b2 * 64, N_FUNC, Xb);
        else          proj_mfma<64>(xa, wpka, ba_, ha, (b2 - NBF) * 64, N_API, Xb);
    }
}

// ---- async DMA: stage rows [c0,c1) of src (via col, or identity) ----
__device__ __forceinline__ void issue_rows(const u16* __restrict__ src_h,
        const int* __restrict__ col, int c0, int c1, u16* stage, int t)
{
    const int w = t >> 6, lane = t & 63;
    const int cnt = c1 - c0;
    for (int le0 = w * 8; le0 < cnt; le0 += 32) {
        int ge = c0 + min(le0 + (lane >> 3), cnt - 1);
        int srow = col ? col[ge] : ge;
        const u16* gp = src_h + (size_t)srow * H + (lane & 7) * 8;
        __builtin_amdgcn_global_load_lds(
            (const __attribute__((address_space(1))) u32*)gp,
            (__attribute__((address_space(3))) u32*)(stage + le0 * 64),
            16, 0, 0);
    }
}

__device__ __forceinline__ void consume_rows(const u16* stage, const int s4[4],
        const int e4[4], int c0, int c1, int L, float4 acc[4])
{
    #pragma unroll
    for (int p = 0; p < 4; ++p) {
        int jlo = max(s4[p], c0), jhi = min(e4[p], c1);
        for (int j = jlo; j < jhi; ++j) {
            ushort4 v = *reinterpret_cast<const ushort4*>(stage + (size_t)(j - c0) * 64 + L * 4);
            addb(acc[p], v);
        }
    }
}

// ---- MFMA GEMM, A from swizzled bf16 Xb tile ----
__device__ __forceinline__ void gemm_mfma_X(const u16* Xb, const u16* __restrict__ wpk,
        int wv, int lane, f32x4 acc[4])
{
    const int r = 16 * wv + (lane & 15);
    #pragma unroll
    for (int kt = 0; kt < 2; ++kt) {
        bf16x8 a = *reinterpret_cast<const bf16x8*>(
            Xb + r * 64 + (((kt * 4 + (lane >> 4)) ^ (r & 7)) << 3));
        #pragma unroll
        for (int nt = 0; nt < 4; ++nt) {
            bf16x8 bh = *reinterpret_cast<const bf16x8*>(wpk + ((kt * 256 + nt * 64 + lane) << 3));
            acc[nt] = __builtin_amdgcn_mfma_f32_16x16x32_bf16(a, bh, acc[nt], 0, 0, 0);
            bf16x8 bl = *reinterpret_cast<const bf16x8*>(wpk + 4096 + ((kt * 256 + nt * 64 + lane) << 3));
            acc[nt] = __builtin_amdgcn_mfma_f32_16x16x32_bf16(a, bl, acc[nt], 0, 0, 0);
        }
    }
}

// ---- MFMA GEMM, A from LINEAR bf16 stage rows ----
__device__ __forceinline__ void gemm_mfma_S(const u16* stage, const u16* __restrict__ wpk,
        int wv, int lane, f32x4 acc[4])
{
    const int r = 16 * wv + (lane & 15);
    #pragma unroll
    for (int kt = 0; kt < 2; ++kt) {
        bf16x8 a = *reinterpret_cast<const bf16x8*>(
            stage + r * 64 + kt * 32 + ((lane >> 4) << 3));
        #pragma unroll
        for (int nt = 0; nt < 4; ++nt) {
            bf16x8 bh = *reinterpret_cast<const bf16x8*>(wpk + ((kt * 256 + nt * 64 + lane) << 3));
            acc[nt] = __builtin_amdgcn_mfma_f32_16x16x32_bf16(a, bh, acc[nt], 0, 0, 0);
            bf16x8 bl = *reinterpret_cast<const bf16x8*>(wpk + 4096 + ((kt * 256 + nt * 64 + lane) << 3));
            acc[nt] = __builtin_amdgcn_mfma_f32_16x16x32_bf16(a, bl, acc[nt], 0, 0, 0);
        }
    }
}

__device__ __forceinline__ void store_agg(u16* Xb, int n, int L, float4 a)
{
    *reinterpret_cast<ushort4*>(Xb + n * 64 + (((L >> 1) ^ (n & 7)) << 3) + ((L & 1) << 2)) = f2b4(a);
}

// ---- fused layer: DMA-staged gather + MFMA GEMMs; fused mean-pool on last layer ----
__global__ __launch_bounds__(256, 5) void layer_both(
        const u16* __restrict__ hf_old, const u16* __restrict__ ha_old,
        u16* __restrict__ hf_new, u16* __restrict__ ha_new,
        const int* __restrict__ rpC, const int* __restrict__ colC,
        const int* __restrict__ rpU, const int* __restrict__ colU,
        const int* __restrict__ rpA, const int* __restrict__ colA,
        const u16* __restrict__ pk_r, const u16* __restrict__ pk_lc,
        const u16* __restrict__ pk_lu,
        const u16* __restrict__ pk_ruse, const u16* __restrict__ pk_luse,
        const float* __restrict__ bias_c, const float* __restrict__ bias_u,
        const float* __restrict__ bias_a,
        float* __restrict__ psh)
{
    __shared__ __align__(16) u16 Xb[64 * 64];       // 8 KB bf16 tile
    __shared__ __align__(16) u16 stage[SCAP * 64];  // 20 KB
    const int b = blockIdx.x;
    const int t = threadIdx.x;
    const int L = t & 15, g = t >> 4;
    const int wv = t >> 6, lane = t & 63;
    const float4 z4 = make_float4(0.f, 0.f, 0.f, 0.f);

    f32x4 acc[4];
    #pragma unroll
    for (int j = 0; j < 4; ++j) acc[j] = (f32x4){0.f, 0.f, 0.f, 0.f};

    if (b < NBF) {
        const int i0 = b * 64;
        int s1[4], e1[4];
        #pragma unroll
        for (int p = 0; p < 4; ++p) {
            int node = i0 + p * 16 + g;
            s1[p] = rpC[node]; e1[p] = rpC[node + 1];
        }
        const int be0 = rpC[i0], be1 = rpC[i0 + 64];
        float4 a1[4];
        #pragma unroll
        for (int p = 0; p < 4; ++p) a1[p] = z4;
        for (int c0 = be0; c0 < be1; c0 += SCAP) {
            int c1 = min(c0 + SCAP, be1);
            issue_rows(hf_old, colC, c0, c1, stage, t);
            __syncthreads();
            consume_rows(stage, s1, e1, c0, c1, L, a1);
            __syncthreads();
        }
        #pragma unroll
        for (int p = 0; p < 4; ++p) {
            int n = p * 16 + g;
            scl4(a1[p], 1.0f / (float)max(e1[p] - s1[p], 1));
            store_agg(Xb, n, L, a1[p]);
        }
        __syncthreads();
        int s2[4], e2[4];
        #pragma unroll
        for (int p = 0; p < 4; ++p) {
            int node = i0 + p * 16 + g;
            s2[p] = rpU[node]; e2[p] = rpU[node + 1];
        }
        const int ue0 = rpU[i0], ue1 = rpU[i0 + 64];
        int uc1 = min(ue0 + SCAP, ue1);
        if (ue1 > ue0) issue_rows(ha_old, colU, ue0, uc1, stage, t);
        gemm_mfma_X(Xb, pk_lc, wv, lane, acc);
        __syncthreads();
        float4 a2[4];
        #pragma unroll
        for (int p = 0; p < 4; ++p) a2[p] = z4;
        if (ue1 > ue0) consume_rows(stage, s2, e2, ue0, uc1, L, a2);
        for (int c0 = uc1; c0 < ue1; c0 += SCAP) {
            int c1 = min(c0 + SCAP, ue1);
            __syncthreads();
            issue_rows(ha_old, colU, c0, c1, stage, t);
            __syncthreads();
            consume_rows(stage, s2, e2, c0, c1, L, a2);
        }
        __syncthreads();
        #pragma unroll
        for (int p = 0; p < 4; ++p) {
            int n = p * 16 + g;
            scl4(a2[p], 1.0f / (float)max(e2[p] - s2[p], 1));
            store_agg(Xb, n, L, a2[p]);
        }
        __syncthreads();
        issue_rows(hf_old, nullptr, i0, i0 + 64, stage, t);
        gemm_mfma_X(Xb, pk_lu, wv, lane, acc);
        __syncthreads();
        gemm_mfma_S(stage, pk_r, wv, lane, acc);
        #pragma unroll
        for (int nt = 0; nt < 4; ++nt) {
            int col = nt * 16 + (lane & 15);
            float bvv = bias_c[col] + bias_u[col];
            #pragma unroll
            for (int rg = 0; rg < 4; ++rg) {
                int row = 16 * wv + (lane >> 4) * 4 + rg;
                Xb[row * 64 + col] = f2bf(fmaxf(acc[nt][rg] + bvv, 0.f));
            }
        }
        __syncthreads();
        const int og = t & 15, ng = t >> 4;
        float4 s = z4;
        #pragma unroll
        for (int j = 0; j < 4; ++j) {
            int node = i0 + ng * 4 + j;
            ushort4 v = *reinterpret_cast<const ushort4*>(Xb + (ng * 4 + j) * 64 + og * 4);
            *reinterpret_cast<ushort4*>(hf_new + (size_t)node * H + og * 4) = v;
            if (psh) addb(s, v);
        }
        if (psh) {
            __syncthreads();
            float4* X4 = reinterpret_cast<float4*>(Xb);
            X4[ng * 16 + og] = s;
            __syncthreads();
            if (ng == 0) {
                float4 tot = z4;
                #pragma unroll
                for (int q = 0; q < 16; ++q) add4(tot, X4[q * 16 + og]);
                float* dst = psh + (size_t)(b & (NSHADOW - 1)) * 128 + og * 4;
                atomicAdd(dst + 0, tot.x); atomicAdd(dst + 1, tot.y);
                atomicAdd(dst + 2, tot.z); atomicAdd(dst + 3, tot.w);
            }
        }
    } else {
        const int i0 = (b - NBF) * 64;
        const int nTop = min(i0 + 64, N_API);
        int s1[4], e1[4];
        #pragma unroll
        for (int p = 0; p < 4; ++p) {
            int node = i0 + p * 16 + g;
            if (node < N_API) { s1[p] = rpA[node]; e1[p] = rpA[node + 1]; }
            else { s1[p] = 0; e1[p] = 0; }
        }
        const int be0 = rpA[i0], be1 = rpA[nTop];
        float4 a1[4];
        #pragma unroll
        for (int p = 0; p < 4; ++p) a1[p] = z4;
        for (int c0 = be0; c0 < be1; c0 += SCAP) {
            int c1 = min(c0 + SCAP, be1);
            issue_rows(hf_old, colA, c0, c1, stage, t);
            __syncthreads();
            consume_rows(stage, s1, e1, c0, c1, L, a1);
            __syncthreads();
        }
        #pragma unroll
        for (int p = 0; p < 4; ++p) {
            int n = p * 16 + g;
            scl4(a1[p], 1.0f / (float)max(e1[p] - s1[p], 1));
            store_agg(Xb, n, L, a1[p]);
        }
        __syncthreads();
        issue_rows(ha_old, nullptr, i0, nTop, stage, t);
        gemm_mfma_X(Xb, pk_luse, wv, lane, acc);
        __syncthreads();
        gemm_mfma_S(stage, pk_ruse, wv, lane, acc);
        #pragma unroll
        for (int nt = 0; nt < 4; ++nt) {
            int col = nt * 16 + (lane & 15);
            float bvv = bias_a[col];
            #pragma unroll
            for (int rg = 0; rg < 4; ++rg) {
                int row = 16 * wv + (lane >> 4) * 4 + rg;
                Xb[row * 64 + col] = f2bf(fmaxf(acc[nt][rg] + bvv, 0.f));
            }
        }
        __syncthreads();
        const int og = t & 15, ng = t >> 4;
        float4 s = z4;
        #pragma unroll
        for (int j = 0; j < 4; ++j) {
            int node = i0 + ng * 4 + j;
            if (node < N_API) {
                ushort4 v = *reinterpret_cast<const ushort4*>(Xb + (ng * 4 + j) * 64 + og * 4);
                *reinterpret_cast<ushort4*>(ha_new + (size_t)node * H + og * 4) = v;
                if (psh) addb(s, v);
            }
        }
        if (psh) {
            __syncthreads();
            float4* X4 = reinterpret_cast<float4*>(Xb);
            X4[ng * 16 + og] = s;
            __syncthreads();
            if (ng == 0) {
                float4 tot = z4;
                #pragma unroll
                for (int q = 0; q < 16; ++q) add4(tot, X4[q * 16 + og]);
                float* dst = psh + (size_t)(b & (NSHADOW - 1)) * 128 + 64 + og * 4;
                atomicAdd(dst + 0, tot.x); atomicAdd(dst + 1, tot.y);
                atomicAdd(dst + 2, tot.z); atomicAdd(dst + 3, tot.w);
            }
        }
    }
}

__global__ __launch_bounds__(128) void classifier_kernel(const float* __restrict__ shadows,
        const float* __restrict__ Wc1, const float* __restrict__ bc1,
        const float* __restrict__ Wc2, const float* __restrict__ bc2,
        float* __restrict__ out)
{
    __shared__ float ps[128];
    __shared__ float z1[64];
    int t = threadIdx.x;
    float s = 0.f;
    for (int q = 0; q < NSHADOW; ++q) s += shadows[q * 128 + t];
    ps[t] = s * (t < 64 ? (1.0f / N_FUNC) : (1.0f / N_API));
    __syncthreads();
    if (t < 64) {
        float a = bc1[t];
        for (int k = 0; k < 128; ++k) a = fmaf(ps[k], Wc1[t * 128 + k], a);
        z1[t] = fmaxf(a, 0.f);
    }
    __syncthreads();
    if (t < 2) {
        float a = bc2[t];
        for (int j = 0; j < 64; ++j) a = fmaf(z1[j], Wc2[t * 64 + j], a);
        out[t] = a;
    }
}

extern "C" void kernel_launch(void* const* d_in, const int* in_sizes, int n_in,
                              void* d_out, int out_size, void* d_ws, size_t ws_size,
                              hipStream_t stream)
{
    const float* x_func    = (const float*)d_in[0];
    const float* x_api     = (const float*)d_in[1];
    const float* w_in_func = (const float*)d_in[2];
    const float* b_in_func = (const float*)d_in[3];
    const float* w_in_api  = (const float*)d_in[4];
    const float* b_in_api  = (const float*)d_in[5];
    const float* Wl_calls  = (const float*)d_in[6];
    const float* bl_calls  = (const float*)d_in[7];
    const float* Wr_calls  = (const float*)d_in[8];
    const float* Wl_uses   = (const float*)d_in[9];
    const float* bl_uses   = (const float*)d_in[10];
    const float* Wr_uses   = (const float*)d_in[11];
    const float* Wl_usedby = (const float*)d_in[12];
    const float* bl_usedby = (const float*)d_in[13];
    const float* Wr_usedby = (const float*)d_in[14];
    const float* Wc1       = (const float*)d_in[15];
    const float* bc1       = (const float*)d_in[16];
    const float* Wc2       = (const float*)d_in[17];
    const float* bc2       = (const float*)d_in[18];
    const int*   ei_calls  = (const int*)d_in[19];
    const int*   ei_uses   = (const int*)d_in[20];
    const int*   ei_usedby = (const int*)d_in[21];
    const int E = in_sizes[19] / 2;

    float* ws = (float*)d_ws;
    size_t off = 0;
    u16* hf0 = (u16*)(ws + off); off += (size_t)N_FUNC * 32;
    u16* hf1 = (u16*)(ws + off); off += (size_t)N_FUNC * 32;
    u16* ha0 = (u16*)(ws + off); off += (size_t)N_API * 32;
    u16* ha1 = (u16*)(ws + off); off += (size_t)N_API * 32;
    u16* wpk = (u16*)(ws + off); off += 53248;   // 106496 u16 packed weights
    int* bktC = (int*)(ws + off); off += NBK;
    int* bktU = (int*)(ws + off); off += NBK;
    int* bktA = (int*)(ws + off); off += NBK;
    float* shadows = ws + off; off += NSHADOW * 128;
    int* bbC = (int*)(ws + off); off += NBK;
    int* bbU = (int*)(ws + off); off += NBK;
    int* bbA = (int*)(ws + off); off += NBK;
    int* rpC = (int*)(ws + off); off += N_FUNC + 1;
    int* rpU = (int*)(ws + off); off += N_FUNC + 1;
    int* rpA = (int*)(ws + off); off += N_API + 1;
    int* colC = (int*)(ws + off); off += E;
    int* colU = (int*)(ws + off); off += E;
    int* colA = (int*)(ws + off); off += E;
    int* beC = (int*)(ws + off); off += (size_t)NBK * BCAP;
    int* beU = (int*)(ws + off); off += (size_t)NBK * BCAP;
    int* beA = (int*)(ws + off); off += (size_t)NBK * BCAP;

    const int nbPerRel = (E + EPB - 1) / EPB;

    hipMemsetAsync(bktC, 0, (size_t)(3 * NBK + NSHADOW * 128) * sizeof(float), stream);

    prep_and_binA<<<PREPB + 3 * nbPerRel, 256, 0, stream>>>(
            w_in_func, w_in_api, Wl_calls, Wr_calls, Wl_uses, Wr_uses,
            Wl_usedby, Wr_usedby, wpk,
            ei_calls, ei_calls + E, ei_usedby, ei_usedby + E, ei_uses, ei_uses + E,
            bktC, bktU, bktA, beC, beU, beA, E, nbPerRel);

    scan_buckets<<<1, 256, 0, stream>>>(bktC, bktU, bktA, bbC, bbU, bbA);

    u16* wpkf = wpk;
    u16* wpka = wpk + 16384;
    u16* wpkL = wpk + 24576;
    u16 *pk_r[NLAYERS], *pk_lc[NLAYERS], *pk_lu[NLAYERS], *pk_luse[NLAYERS], *pk_ruse[NLAYERS];
    for (int l = 0; l < NLAYERS; ++l) {
        pk_r[l]    = wpkL + (size_t)(l * 5 + 0) * 8192;
        pk_lc[l]   = wpkL + (size_t)(l * 5 + 1) * 8192;
        pk_lu[l]   = wpkL + (size_t)(l * 5 + 2) * 8192;
        pk_luse[l] = wpkL + (size_t)(l * 5 + 3) * 8192;
        pk_ruse[l] = wpkL + (size_t)(l * 5 + 4) * 8192;
    }

    binB_and_proj<<<3 * NBK + NBF + NBA, 256, 0, stream>>>(
            beC, beU, beA, bktC, bktU, bktA, bbC, bbU, bbA,
            rpC, rpU, rpA, colC, colU, colA,
            x_func, wpkf, b_in_func, hf0,
            x_api, wpka, b_in_api, ha0);

    u16* hf[2] = { hf0, hf1 };
    u16* ha[2] = { ha0, ha1 };
    for (int l = 0; l < NLAYERS; ++l) {
        int cur = l & 1, nxt = cur ^ 1;
        layer_both<<<NBF + NBA, 256, 0, stream>>>(
                hf[cur], ha[cur], hf[nxt], ha[nxt],
                rpC, colC, rpU, colU, rpA, colA,
                pk_r[l], pk_lc[l], pk_lu[l], pk_ruse[l], pk_luse[l],
                bl_calls + l * 64, bl_usedby + l * 64, bl_uses + l * 64,
                (l == NLAYERS - 1) ? shadows : nullptr);
    }

    classifier_kernel<<<1, 128, 0, stream>>>(shadows, Wc1, bc1, Wc2, bc2, (float*)d_out);
}